// Round 2
// baseline (145.267 us; speedup 1.0000x reference)
//
#include <hip/hip_runtime.h>

// multi_triples_lstm v16: v15 structure + transcendental-pipe offload.
// Theory: v14==v15 durations at wildly different structures/occupancy =>
// kernel is throughput-bound on the (quarter-rate, CU-shared) transcendental
// unit: 56 trans/step/wave * 8 cyc fits the 118K-cycle duration exactly.
// Fix: cut trans instrs 56 -> 24 per step:
//  - Ei/Ef/Eo (sigmoid-gate exps) computed as bit-trick exp2 (magic round +
//    deg-5 poly, rel err 2.5e-6) on the half-idle main VALU pipe.
//  - reciprocals merged pairwise across chains: rcp(a*b) + 2 muls recovers
//    1/a and 1/b  (4 rcp -> 2 rcp per site per chain-pair).
//  - Eg, Ec stay on the trans unit (Ec is on the serial c->h critical path).
// Everything else (barrier-free recurrence, W-row permutation, staging,
// epilogue) identical to v15.
#define XSTRIDE 1072
#define ZOFF    (16 * XSTRIDE)
#define LDS_BYTES (ZOFF + 32)

typedef _Float16 f16x8 __attribute__((ext_vector_type(8)));
typedef __fp16   fp16x2 __attribute__((ext_vector_type(2)));
typedef float    f32x4 __attribute__((ext_vector_type(4)));
typedef float    f32x2 __attribute__((ext_vector_type(2)));

#define LOG2E     1.44269504088896f
#define TWO_LOG2E 2.88539008177793f

// packed-pair exp2 on the main VALU pipe (no v_exp_f32).
// |x| clamped to 60 so the exponent bit-add needs no denormal/overflow path.
// deg-5 Taylor of 2^f on [-0.5,0.5]: rel err < 2.5e-6 (absmax floor is ~5e-4
// from fp16 h quantization, so this is invisible).
static __device__ __forceinline__ f32x2 exp2_pk(f32x2 x)
{
    float x0 = fminf(fmaxf(x.x, -60.0f), 60.0f);
    float x1 = fminf(fmaxf(x.y, -60.0f), 60.0f);
    const float MG = 12582912.0f;               // 1.5 * 2^23
    float m0 = x0 + MG, m1 = x1 + MG;           // round-to-nearest in mantissa
    float k0 = m0 - MG, k1 = m1 - MG;           // k = rndne(x)
    float f0 = x0 - k0, f1 = x1 - k1;           // f in [-0.5, 0.5]
    const float C5 = 1.3333558e-3f, C4 = 9.6181291e-3f, C3 = 5.5504109e-2f,
                C2 = 2.4022651e-1f, C1 = 6.9314718e-1f;
    float p0 = C5 * f0 + C4,       p1 = C5 * f1 + C4;
    p0 = p0 * f0 + C3;             p1 = p1 * f1 + C3;
    p0 = p0 * f0 + C2;             p1 = p1 * f1 + C2;
    p0 = p0 * f0 + C1;             p1 = p1 * f1 + C1;
    p0 = p0 * f0 + 1.0f;           p1 = p1 * f1 + 1.0f;
    int e0 = (__float_as_int(m0) - 0x4B400000) << 23;   // k << 23
    int e1 = (__float_as_int(m1) - 0x4B400000) << 23;
    f32x2 r;
    r.x = __int_as_float(__float_as_int(p0) + e0);
    r.y = __int_as_float(__float_as_int(p1) + e1);
    return r;
}

__global__ __launch_bounds__(64, 2)
void lstm_fused(const int* __restrict__ objs,
                const float* __restrict__ boxes,
                const int* __restrict__ preds,
                const int* __restrict__ subj,
                const float* __restrict__ obj_emb,
                const float* __restrict__ pred_emb,
                const float* __restrict__ W_ih,
                const float* __restrict__ W_hh,
                const float* __restrict__ b_ih,
                const float* __restrict__ b_hh,
                const float* __restrict__ fc2_W,
                const float* __restrict__ fc2_b,
                float* __restrict__ out)
{
    extern __shared__ char smem[];
    const int lane = threadIdx.x;        // 0..63
    const int quad = lane >> 4;          // 0..3: K-slice of MFMA frags
    const int cidx = lane & 15;          // batch column

    if (lane < 8) ((int*)(smem + ZOFF))[lane] = 0;

    // ---- stage x features (fp16) for this wave's 16 batches ----
    {
        const int b = lane >> 2;
        const int j = lane & 3;
        const long gb = (long)blockIdx.x * 16 + b;
        const int* orow = objs + gb * 32;
        const int* prow = preds + gb * 32;
        const int* srow = subj + gb * 32;
        const float* brow = boxes + gb * 128;
        char* xrow = smem + b * XSTRIDE;
        #pragma unroll
        for (int tt = 0; tt < 8; ++tt) {
            int t = j + tt * 4;
            int o = orow[t], p = prow[t], sv = srow[t];
            const float* eo = obj_emb + o * 5;
            const float* ep = pred_emb + p * 5;
            float4 bx = *(const float4*)(brow + t * 4);
            f16x8 lo, hi;
            lo[0]=(_Float16)eo[0]; lo[1]=(_Float16)eo[1]; lo[2]=(_Float16)eo[2];
            lo[3]=(_Float16)eo[3]; lo[4]=(_Float16)eo[4];
            lo[5]=(_Float16)ep[0]; lo[6]=(_Float16)ep[1]; lo[7]=(_Float16)ep[2];
            hi[0]=(_Float16)ep[3]; hi[1]=(_Float16)ep[4];
            hi[2]=(_Float16)(sv==0 ? 1.0f : 0.0f);
            hi[3]=(_Float16)(sv==1 ? 1.0f : 0.0f);
            hi[4]=(_Float16)bx.x; hi[5]=(_Float16)bx.y;
            hi[6]=(_Float16)bx.z; hi[7]=(_Float16)bx.w;
            *(f16x8*)(xrow + t * 32)      = lo;
            *(f16x8*)(xrow + t * 32 + 16) = hi;
        }
    }

    // ---- W fragments + bias ----
    f16x8 WH[8], WX[8];
    f32x4 bias[8];
    #pragma unroll
    for (int a = 0; a < 8; ++a) {
        const int gate = a >> 1;
        const float scale = (gate == 2) ? TWO_LOG2E : -LOG2E;
        const int n = gate * 32 + 8 * (cidx >> 2) + 4 * (a & 1) + (cidx & 3);
        const float* wr = W_hh + n * 32 + quad * 8;
        float4 w0 = *(const float4*)(wr);
        float4 w1 = *(const float4*)(wr + 4);
        f16x8 h8;
        h8[0]=(_Float16)(w0.x*scale); h8[1]=(_Float16)(w0.y*scale);
        h8[2]=(_Float16)(w0.z*scale); h8[3]=(_Float16)(w0.w*scale);
        h8[4]=(_Float16)(w1.x*scale); h8[5]=(_Float16)(w1.y*scale);
        h8[6]=(_Float16)(w1.z*scale); h8[7]=(_Float16)(w1.w*scale);
        WH[a] = h8;
        f16x8 x8;
        if (quad < 2) {
            const float* xr = W_ih + n * 16 + quad * 8;
            float4 u0 = *(const float4*)(xr);
            float4 u1 = *(const float4*)(xr + 4);
            x8[0]=(_Float16)(u0.x*scale); x8[1]=(_Float16)(u0.y*scale);
            x8[2]=(_Float16)(u0.z*scale); x8[3]=(_Float16)(u0.w*scale);
            x8[4]=(_Float16)(u1.x*scale); x8[5]=(_Float16)(u1.y*scale);
            x8[6]=(_Float16)(u1.z*scale); x8[7]=(_Float16)(u1.w*scale);
        } else {
            #pragma unroll
            for (int jj = 0; jj < 8; ++jj) x8[jj] = (_Float16)0.0f;
        }
        WX[a] = x8;
        const int nb = gate * 32 + 8 * quad + 4 * (a & 1);
        float4 bi = *(const float4*)(b_ih + nb);
        float4 bh = *(const float4*)(b_hh + nb);
        f32x4 bb = {(bi.x+bh.x)*scale, (bi.y+bh.y)*scale,
                    (bi.z+bh.z)*scale, (bi.w+bh.w)*scale};
        bias[a] = bb;
    }

    __syncthreads();   // staging visible

    // ---- recurrence: barrier-free ----
    const bool qlow = (quad < 2);
    int xaddr = qlow ? (cidx * XSTRIDE + quad * 16) : ZOFF;
    const int xinc = qlow ? 32 : 0;

    f16x8 xfrag = *(const f16x8*)(smem + xaddr); xaddr += xinc;
    f32x4 accp[8];
    #pragma unroll
    for (int a = 0; a < 8; ++a)
        accp[a] = __builtin_amdgcn_mfma_f32_16x16x32_f16(WX[a], xfrag, bias[a], 0, 0, 0);

    union { int i[4]; f16x8 v; } hf;
    hf.i[0]=0; hf.i[1]=0; hf.i[2]=0; hf.i[3]=0;
    const f32x2 zz = {0.0f, 0.0f};
    f32x2 cst[4] = {zz, zz, zz, zz};
    f32x2 hv[4];
    const f32x2 one = {1.0f, 1.0f};

    #pragma unroll 4
    for (int t = 0; t < 32; ++t) {
        f32x4 acc[8];
        #pragma unroll
        for (int a = 0; a < 8; ++a)
            acc[a] = __builtin_amdgcn_mfma_f32_16x16x32_f16(WH[a], hf.v, accp[a], 0, 0, 0);

        f16x8 xn = *(const f16x8*)(smem + xaddr); xaddr += xinc;

        // two chain-PAIRS; within a pair the rcp sites are merged.
        // pp=0 -> chains {0,1} (accs 0,2,4,6); pp=1 -> chains {2,3} (accs 1,3,5,7)
        #pragma unroll
        for (int pp = 0; pp < 2; ++pp) {
            const f32x4 aI = acc[0+pp], aF = acc[2+pp], aG = acc[4+pp], aO = acc[6+pp];
            f32x2 ziU = {aI[0], aI[1]}, ziV = {aI[2], aI[3]};
            f32x2 zfU = {aF[0], aF[1]}, zfV = {aF[2], aF[3]};
            f32x2 zoU = {aO[0], aO[1]}, zoV = {aO[2], aO[3]};
            // Eg on the trans unit (leaf, issue early)
            f32x2 EgU = {__builtin_amdgcn_exp2f(aG[0]), __builtin_amdgcn_exp2f(aG[1])};
            f32x2 EgV = {__builtin_amdgcn_exp2f(aG[2]), __builtin_amdgcn_exp2f(aG[3])};
            // sigmoid-gate exps on the main VALU pipe
            f32x2 EiU = exp2_pk(ziU), EiV = exp2_pk(ziV);
            f32x2 EfU = exp2_pk(zfU), EfV = exp2_pk(zfV);
            f32x2 EoU = exp2_pk(zoU), EoV = exp2_pk(zoV);

            f32x2 t1U = EiU + one,          t1V = EiV + one;
            f32x2 digU = t1U * EgU + t1U,   digV = t1V * EgV + t1V;   // (1+Ei)(1+Eg)
            f32x2 tfU = EfU + one,          tfV = EfV + one;
            f32x2 nnU = (EgU - one) * tfU + cst[2*pp]   * digU;
            f32x2 nnV = (EgV - one) * tfV + cst[2*pp+1] * digV;
            f32x2 denU = tfU * digU,        denV = tfV * digV;
            // merged reciprocal: 2 rcp recover 4 values
            f32x2 P = denU * denV;
            f32x2 R = {__builtin_amdgcn_rcpf(P.x), __builtin_amdgcn_rcpf(P.y)};
            f32x2 cU = nnU * (R * denV);
            f32x2 cV = nnV * (R * denU);
            cst[2*pp] = cU; cst[2*pp+1] = cV;
            f32x2 EcU = {__builtin_amdgcn_exp2f(cU.x * TWO_LOG2E),
                         __builtin_amdgcn_exp2f(cU.y * TWO_LOG2E)};
            f32x2 EcV = {__builtin_amdgcn_exp2f(cV.x * TWO_LOG2E),
                         __builtin_amdgcn_exp2f(cV.y * TWO_LOG2E)};
            f32x2 toU = EoU + one,          toV = EoV + one;
            f32x2 dhU = toU * EcU + toU,    dhV = toV * EcV + toV;    // (1+Eo)(1+Ec)
            f32x2 Q = dhU * dhV;
            f32x2 S = {__builtin_amdgcn_rcpf(Q.x), __builtin_amdgcn_rcpf(Q.y)};
            hv[2*pp]   = (EcU - one) * (S * dhV);
            hv[2*pp+1] = (EcV - one) * (S * dhU);
            union { fp16x2 h; int i; } pk0, pk1;
            pk0.h = __builtin_amdgcn_cvt_pkrtz(hv[2*pp].x,   hv[2*pp].y);
            pk1.h = __builtin_amdgcn_cvt_pkrtz(hv[2*pp+1].x, hv[2*pp+1].y);
            hf.i[2*pp]   = pk0.i;
            hf.i[2*pp+1] = pk1.i;
        }

        #pragma unroll
        for (int a = 0; a < 8; ++a)
            accp[a] = __builtin_amdgcn_mfma_f32_16x16x32_f16(WX[a], xn, bias[a], 0, 0, 0);
    }

    // ---- fc2 epilogue (wave-local) ----
    __syncthreads();
    {
        char* s0 = smem + cidx * 144 + quad * 32;
        float4 lo4 = {hv[0].x, hv[0].y, hv[1].x, hv[1].y};
        float4 hi4 = {hv[2].x, hv[2].y, hv[3].x, hv[3].y};
        *(float4*)s0        = lo4;
        *(float4*)(s0 + 16) = hi4;
    }
    __syncthreads();
    {
        const int b = lane >> 2, j = lane & 3;
        const float* hrow = (const float*)(smem + b * 144);
        const float* fw = fc2_W + j * 32;
        float s = fc2_b[j];
        #pragma unroll
        for (int k = 0; k < 8; ++k) {
            float4 hvv = *(const float4*)(hrow + k * 4);
            float4 wv4 = *(const float4*)(fw + k * 4);
            s += wv4.x*hvv.x + wv4.y*hvv.y + wv4.z*hvv.z + wv4.w*hvv.w;
        }
        s = fminf(fmaxf(s, 0.0f), 1.0f);
        out[(long)blockIdx.x * 64 + lane] = s;
    }
}

extern "C" void kernel_launch(void* const* d_in, const int* in_sizes, int n_in,
                              void* d_out, int out_size, void* d_ws, size_t ws_size,
                              hipStream_t stream)
{
    // inputs: 0 objs(i32) 1 boxes(f32) 2 preds(i32) 3 subj(i32) 4 target(unused)
    //         5 obj_emb 6 pred_emb 7 W_ih 8 W_hh 9 b_ih 10 b_hh 11 fc2_W 12 fc2_b
    lstm_fused<<<2048, 64, LDS_BYTES, stream>>>(
        (const int*)d_in[0], (const float*)d_in[1], (const int*)d_in[2],
        (const int*)d_in[3],
        (const float*)d_in[5], (const float*)d_in[6],
        (const float*)d_in[7], (const float*)d_in[8],
        (const float*)d_in[9], (const float*)d_in[10],
        (const float*)d_in[11], (const float*)d_in[12],
        (float*)d_out);
}

// Round 3
// 143.728 us; speedup vs baseline: 1.0107x; 1.0107x over previous
//
#include <hip/hip_runtime.h>

// multi_triples_lstm v17: v15 structure + PACKED poly-exp offload.
// Model (fits v14/v15/v16): trans unit ≈ 8 lanes/cyc/CU; v14/v15 saturate it
// (97%), duration = trans-lanes / 8. v16 regressed because its poly-exp was
// scalar (26 ops/pair) -> VALU-issue became a worse wall.
// v17: exp2 poly written in f32x2 so clang emits v_pk_fma_f32 (12 ops/pair),
// and Eg joins Ei/Ef/Eo on the poly path. Trans per step per wave: 56 -> 16
// (8 exp for Ec on the serial c->h path + 8 merged rcp).
// Everything else (barrier-free recurrence, W-row permutation, staging,
// merged reciprocals, epilogue) identical to v16.
#define XSTRIDE 1072
#define ZOFF    (16 * XSTRIDE)
#define LDS_BYTES (ZOFF + 32)

typedef _Float16 f16x8 __attribute__((ext_vector_type(8)));
typedef __fp16   fp16x2 __attribute__((ext_vector_type(2)));
typedef float    f32x4 __attribute__((ext_vector_type(4)));
typedef float    f32x2 __attribute__((ext_vector_type(2)));

#define LOG2E     1.44269504088896f
#define TWO_LOG2E 2.88539008177793f

// Packed exp2 on the main VALU pipe: all f32 arithmetic in f32x2 so the
// backend selects VOP3P packed-f32 ops (v_pk_add_f32 / v_pk_fma_f32).
// Magic-number round-to-nearest + deg-5 poly on [-0.5,0.5] (rel err 2.5e-6;
// invisible under the ~5e-4 fp16-h floor). No clamp: |arg| is data-bounded
// (~<=40 incl. the 2*log2e g-gate scale); the exponent bit-add is exact for
// |k| < ~120. 12 instrs/pair vs v16's 26 scalar.
static __device__ __forceinline__ f32x2 exp2_pk(f32x2 x)
{
    const f32x2 MG = {12582912.0f, 12582912.0f};      // 1.5 * 2^23
    f32x2 m = x + MG;                                  // rndne in mantissa
    f32x2 k = m - MG;                                  // k = rndne(x)
    f32x2 f = x - k;                                   // f in [-0.5, 0.5]
    const f32x2 C5 = {1.3333558e-3f, 1.3333558e-3f};
    const f32x2 C4 = {9.6181291e-3f, 9.6181291e-3f};
    const f32x2 C3 = {5.5504109e-2f, 5.5504109e-2f};
    const f32x2 C2 = {2.4022651e-1f, 2.4022651e-1f};
    const f32x2 C1 = {6.9314718e-1f, 6.9314718e-1f};
    const f32x2 ONE = {1.0f, 1.0f};
    f32x2 p = C5 * f + C4;
    p = p * f + C3;
    p = p * f + C2;
    p = p * f + C1;
    p = p * f + ONE;
    // ldexp via bit-add: as_int(m)<<23 == k<<23 exactly (low 9 bits of the
    // magic's bit pattern are zero, so the shift cancels it mod 2^32).
    int e0 = __float_as_int(m.x) << 23;
    int e1 = __float_as_int(m.y) << 23;
    f32x2 r;
    r.x = __int_as_float(__float_as_int(p.x) + e0);
    r.y = __int_as_float(__float_as_int(p.y) + e1);
    return r;
}

__global__ __launch_bounds__(64, 2)
void lstm_fused(const int* __restrict__ objs,
                const float* __restrict__ boxes,
                const int* __restrict__ preds,
                const int* __restrict__ subj,
                const float* __restrict__ obj_emb,
                const float* __restrict__ pred_emb,
                const float* __restrict__ W_ih,
                const float* __restrict__ W_hh,
                const float* __restrict__ b_ih,
                const float* __restrict__ b_hh,
                const float* __restrict__ fc2_W,
                const float* __restrict__ fc2_b,
                float* __restrict__ out)
{
    extern __shared__ char smem[];
    const int lane = threadIdx.x;        // 0..63
    const int quad = lane >> 4;          // 0..3: K-slice of MFMA frags
    const int cidx = lane & 15;          // batch column

    if (lane < 8) ((int*)(smem + ZOFF))[lane] = 0;

    // ---- stage x features (fp16) for this wave's 16 batches ----
    {
        const int b = lane >> 2;
        const int j = lane & 3;
        const long gb = (long)blockIdx.x * 16 + b;
        const int* orow = objs + gb * 32;
        const int* prow = preds + gb * 32;
        const int* srow = subj + gb * 32;
        const float* brow = boxes + gb * 128;
        char* xrow = smem + b * XSTRIDE;
        #pragma unroll
        for (int tt = 0; tt < 8; ++tt) {
            int t = j + tt * 4;
            int o = orow[t], p = prow[t], sv = srow[t];
            const float* eo = obj_emb + o * 5;
            const float* ep = pred_emb + p * 5;
            float4 bx = *(const float4*)(brow + t * 4);
            f16x8 lo, hi;
            lo[0]=(_Float16)eo[0]; lo[1]=(_Float16)eo[1]; lo[2]=(_Float16)eo[2];
            lo[3]=(_Float16)eo[3]; lo[4]=(_Float16)eo[4];
            lo[5]=(_Float16)ep[0]; lo[6]=(_Float16)ep[1]; lo[7]=(_Float16)ep[2];
            hi[0]=(_Float16)ep[3]; hi[1]=(_Float16)ep[4];
            hi[2]=(_Float16)(sv==0 ? 1.0f : 0.0f);
            hi[3]=(_Float16)(sv==1 ? 1.0f : 0.0f);
            hi[4]=(_Float16)bx.x; hi[5]=(_Float16)bx.y;
            hi[6]=(_Float16)bx.z; hi[7]=(_Float16)bx.w;
            *(f16x8*)(xrow + t * 32)      = lo;
            *(f16x8*)(xrow + t * 32 + 16) = hi;
        }
    }

    // ---- W fragments + bias ----
    f16x8 WH[8], WX[8];
    f32x4 bias[8];
    #pragma unroll
    for (int a = 0; a < 8; ++a) {
        const int gate = a >> 1;
        const float scale = (gate == 2) ? TWO_LOG2E : -LOG2E;
        const int n = gate * 32 + 8 * (cidx >> 2) + 4 * (a & 1) + (cidx & 3);
        const float* wr = W_hh + n * 32 + quad * 8;
        float4 w0 = *(const float4*)(wr);
        float4 w1 = *(const float4*)(wr + 4);
        f16x8 h8;
        h8[0]=(_Float16)(w0.x*scale); h8[1]=(_Float16)(w0.y*scale);
        h8[2]=(_Float16)(w0.z*scale); h8[3]=(_Float16)(w0.w*scale);
        h8[4]=(_Float16)(w1.x*scale); h8[5]=(_Float16)(w1.y*scale);
        h8[6]=(_Float16)(w1.z*scale); h8[7]=(_Float16)(w1.w*scale);
        WH[a] = h8;
        f16x8 x8;
        if (quad < 2) {
            const float* xr = W_ih + n * 16 + quad * 8;
            float4 u0 = *(const float4*)(xr);
            float4 u1 = *(const float4*)(xr + 4);
            x8[0]=(_Float16)(u0.x*scale); x8[1]=(_Float16)(u0.y*scale);
            x8[2]=(_Float16)(u0.z*scale); x8[3]=(_Float16)(u0.w*scale);
            x8[4]=(_Float16)(u1.x*scale); x8[5]=(_Float16)(u1.y*scale);
            x8[6]=(_Float16)(u1.z*scale); x8[7]=(_Float16)(u1.w*scale);
        } else {
            #pragma unroll
            for (int jj = 0; jj < 8; ++jj) x8[jj] = (_Float16)0.0f;
        }
        WX[a] = x8;
        const int nb = gate * 32 + 8 * quad + 4 * (a & 1);
        float4 bi = *(const float4*)(b_ih + nb);
        float4 bh = *(const float4*)(b_hh + nb);
        f32x4 bb = {(bi.x+bh.x)*scale, (bi.y+bh.y)*scale,
                    (bi.z+bh.z)*scale, (bi.w+bh.w)*scale};
        bias[a] = bb;
    }

    __syncthreads();   // staging visible

    // ---- recurrence: barrier-free ----
    const bool qlow = (quad < 2);
    int xaddr = qlow ? (cidx * XSTRIDE + quad * 16) : ZOFF;
    const int xinc = qlow ? 32 : 0;

    f16x8 xfrag = *(const f16x8*)(smem + xaddr); xaddr += xinc;
    f32x4 accp[8];
    #pragma unroll
    for (int a = 0; a < 8; ++a)
        accp[a] = __builtin_amdgcn_mfma_f32_16x16x32_f16(WX[a], xfrag, bias[a], 0, 0, 0);

    union { int i[4]; f16x8 v; } hf;
    hf.i[0]=0; hf.i[1]=0; hf.i[2]=0; hf.i[3]=0;
    const f32x2 zz = {0.0f, 0.0f};
    f32x2 cst[4] = {zz, zz, zz, zz};
    f32x2 hv[4];
    const f32x2 one = {1.0f, 1.0f};

    #pragma unroll 4
    for (int t = 0; t < 32; ++t) {
        f32x4 acc[8];
        #pragma unroll
        for (int a = 0; a < 8; ++a)
            acc[a] = __builtin_amdgcn_mfma_f32_16x16x32_f16(WH[a], hf.v, accp[a], 0, 0, 0);

        f16x8 xn = *(const f16x8*)(smem + xaddr); xaddr += xinc;

        // two chain-PAIRS; within a pair the rcp sites are merged.
        // pp=0 -> chains {0,1} (accs 0,2,4,6); pp=1 -> chains {2,3} (accs 1,3,5,7)
        #pragma unroll
        for (int pp = 0; pp < 2; ++pp) {
            const f32x4 aI = acc[0+pp], aF = acc[2+pp], aG = acc[4+pp], aO = acc[6+pp];
            f32x2 ziU = {aI[0], aI[1]}, ziV = {aI[2], aI[3]};
            f32x2 zfU = {aF[0], aF[1]}, zfV = {aF[2], aF[3]};
            f32x2 zgU = {aG[0], aG[1]}, zgV = {aG[2], aG[3]};
            f32x2 zoU = {aO[0], aO[1]}, zoV = {aO[2], aO[3]};
            // all gate exps on the packed main-VALU pipe (leaf, parallel)
            f32x2 EiU = exp2_pk(ziU), EiV = exp2_pk(ziV);
            f32x2 EfU = exp2_pk(zfU), EfV = exp2_pk(zfV);
            f32x2 EgU = exp2_pk(zgU), EgV = exp2_pk(zgV);
            f32x2 EoU = exp2_pk(zoU), EoV = exp2_pk(zoV);

            f32x2 t1U = EiU + one,          t1V = EiV + one;
            f32x2 digU = t1U * EgU + t1U,   digV = t1V * EgV + t1V;   // (1+Ei)(1+Eg)
            f32x2 tfU = EfU + one,          tfV = EfV + one;
            f32x2 nnU = (EgU - one) * tfU + cst[2*pp]   * digU;
            f32x2 nnV = (EgV - one) * tfV + cst[2*pp+1] * digV;
            f32x2 denU = tfU * digU,        denV = tfV * digV;
            // merged reciprocal: 2 rcp recover 4 values
            f32x2 P = denU * denV;
            f32x2 R = {__builtin_amdgcn_rcpf(P.x), __builtin_amdgcn_rcpf(P.y)};
            f32x2 cU = nnU * (R * denV);
            f32x2 cV = nnV * (R * denU);
            cst[2*pp] = cU; cst[2*pp+1] = cV;
            // Ec stays on the trans unit: it is on the serial c->h critical
            // path and the trans latency is shorter than the poly chain.
            f32x2 EcU = {__builtin_amdgcn_exp2f(cU.x * TWO_LOG2E),
                         __builtin_amdgcn_exp2f(cU.y * TWO_LOG2E)};
            f32x2 EcV = {__builtin_amdgcn_exp2f(cV.x * TWO_LOG2E),
                         __builtin_amdgcn_exp2f(cV.y * TWO_LOG2E)};
            f32x2 toU = EoU + one,          toV = EoV + one;
            f32x2 dhU = toU * EcU + toU,    dhV = toV * EcV + toV;    // (1+Eo)(1+Ec)
            f32x2 Q = dhU * dhV;
            f32x2 S = {__builtin_amdgcn_rcpf(Q.x), __builtin_amdgcn_rcpf(Q.y)};
            hv[2*pp]   = (EcU - one) * (S * dhV);
            hv[2*pp+1] = (EcV - one) * (S * dhU);
            union { fp16x2 h; int i; } pk0, pk1;
            pk0.h = __builtin_amdgcn_cvt_pkrtz(hv[2*pp].x,   hv[2*pp].y);
            pk1.h = __builtin_amdgcn_cvt_pkrtz(hv[2*pp+1].x, hv[2*pp+1].y);
            hf.i[2*pp]   = pk0.i;
            hf.i[2*pp+1] = pk1.i;
        }

        #pragma unroll
        for (int a = 0; a < 8; ++a)
            accp[a] = __builtin_amdgcn_mfma_f32_16x16x32_f16(WX[a], xn, bias[a], 0, 0, 0);
    }

    // ---- fc2 epilogue (wave-local) ----
    __syncthreads();
    {
        char* s0 = smem + cidx * 144 + quad * 32;
        float4 lo4 = {hv[0].x, hv[0].y, hv[1].x, hv[1].y};
        float4 hi4 = {hv[2].x, hv[2].y, hv[3].x, hv[3].y};
        *(float4*)s0        = lo4;
        *(float4*)(s0 + 16) = hi4;
    }
    __syncthreads();
    {
        const int b = lane >> 2, j = lane & 3;
        const float* hrow = (const float*)(smem + b * 144);
        const float* fw = fc2_W + j * 32;
        float s = fc2_b[j];
        #pragma unroll
        for (int k = 0; k < 8; ++k) {
            float4 hvv = *(const float4*)(hrow + k * 4);
            float4 wv4 = *(const float4*)(fw + k * 4);
            s += wv4.x*hvv.x + wv4.y*hvv.y + wv4.z*hvv.z + wv4.w*hvv.w;
        }
        s = fminf(fmaxf(s, 0.0f), 1.0f);
        out[(long)blockIdx.x * 64 + lane] = s;
    }
}

extern "C" void kernel_launch(void* const* d_in, const int* in_sizes, int n_in,
                              void* d_out, int out_size, void* d_ws, size_t ws_size,
                              hipStream_t stream)
{
    // inputs: 0 objs(i32) 1 boxes(f32) 2 preds(i32) 3 subj(i32) 4 target(unused)
    //         5 obj_emb 6 pred_emb 7 W_ih 8 W_hh 9 b_ih 10 b_hh 11 fc2_W 12 fc2_b
    lstm_fused<<<2048, 64, LDS_BYTES, stream>>>(
        (const int*)d_in[0], (const float*)d_in[1], (const int*)d_in[2],
        (const int*)d_in[3],
        (const float*)d_in[5], (const float*)d_in[6],
        (const float*)d_in[7], (const float*)d_in[8],
        (const float*)d_in[9], (const float*)d_in[10],
        (const float*)d_in[11], (const float*)d_in[12],
        (float*)d_out);
}

// Round 4
// 129.507 us; speedup vs baseline: 1.1217x; 1.1098x over previous
//
#include <hip/hip_runtime.h>

// multi_triples_lstm v18: v15 algebra EXACTLY + ROLLED t-loop.
// Post-mortem model (fits v15/v16/v17 to <2%): dur = 23us + 0.54us/KB of
// unrolled loop code -> instruction-fetch streaming is the wall (48-115KB
// unrolled body >> 32KB I$; every wave streams the whole code image from
// L2/L3 once; SQ front-end starves -> VALUBusy pinned ~45% at any VALU count,
// MfmaUtil inverse to duration, FETCH constant).
// Fix: #pragma unroll 1 on the t-loop -> ~1.6KB resident body.
// Everything else (barrier-free recurrence, W-row permutation, staging,
// shared-denominator activations with ALL exps/rcps on the trans unit,
// epilogue) is byte-for-byte v15 semantics.
#define XSTRIDE 1072
#define ZOFF    (16 * XSTRIDE)
#define LDS_BYTES (ZOFF + 32)

typedef _Float16 f16x8 __attribute__((ext_vector_type(8)));
typedef __fp16   fp16x2 __attribute__((ext_vector_type(2)));
typedef float    f32x4 __attribute__((ext_vector_type(4)));
typedef float    f32x2 __attribute__((ext_vector_type(2)));

#define LOG2E     1.44269504088896f
#define TWO_LOG2E 2.88539008177793f

__global__ __launch_bounds__(64, 2)
void lstm_fused(const int* __restrict__ objs,
                const float* __restrict__ boxes,
                const int* __restrict__ preds,
                const int* __restrict__ subj,
                const float* __restrict__ obj_emb,
                const float* __restrict__ pred_emb,
                const float* __restrict__ W_ih,
                const float* __restrict__ W_hh,
                const float* __restrict__ b_ih,
                const float* __restrict__ b_hh,
                const float* __restrict__ fc2_W,
                const float* __restrict__ fc2_b,
                float* __restrict__ out)
{
    extern __shared__ char smem[];
    const int lane = threadIdx.x;        // 0..63
    const int quad = lane >> 4;          // 0..3: K-slice of MFMA frags
    const int cidx = lane & 15;          // batch column

    if (lane < 8) ((int*)(smem + ZOFF))[lane] = 0;

    // ---- stage x features (fp16) for this wave's 16 batches ----
    {
        const int b = lane >> 2;
        const int j = lane & 3;
        const long gb = (long)blockIdx.x * 16 + b;
        const int* orow = objs + gb * 32;
        const int* prow = preds + gb * 32;
        const int* srow = subj + gb * 32;
        const float* brow = boxes + gb * 128;
        char* xrow = smem + b * XSTRIDE;
        #pragma unroll
        for (int tt = 0; tt < 8; ++tt) {
            int t = j + tt * 4;
            int o = orow[t], p = prow[t], sv = srow[t];
            const float* eo = obj_emb + o * 5;
            const float* ep = pred_emb + p * 5;
            float4 bx = *(const float4*)(brow + t * 4);
            f16x8 lo, hi;
            lo[0]=(_Float16)eo[0]; lo[1]=(_Float16)eo[1]; lo[2]=(_Float16)eo[2];
            lo[3]=(_Float16)eo[3]; lo[4]=(_Float16)eo[4];
            lo[5]=(_Float16)ep[0]; lo[6]=(_Float16)ep[1]; lo[7]=(_Float16)ep[2];
            hi[0]=(_Float16)ep[3]; hi[1]=(_Float16)ep[4];
            hi[2]=(_Float16)(sv==0 ? 1.0f : 0.0f);
            hi[3]=(_Float16)(sv==1 ? 1.0f : 0.0f);
            hi[4]=(_Float16)bx.x; hi[5]=(_Float16)bx.y;
            hi[6]=(_Float16)bx.z; hi[7]=(_Float16)bx.w;
            *(f16x8*)(xrow + t * 32)      = lo;
            *(f16x8*)(xrow + t * 32 + 16) = hi;
        }
    }

    // ---- W fragments + bias ----
    f16x8 WH[8], WX[8];
    f32x4 bias[8];
    #pragma unroll
    for (int a = 0; a < 8; ++a) {
        const int gate = a >> 1;
        const float scale = (gate == 2) ? TWO_LOG2E : -LOG2E;
        const int n = gate * 32 + 8 * (cidx >> 2) + 4 * (a & 1) + (cidx & 3);
        const float* wr = W_hh + n * 32 + quad * 8;
        float4 w0 = *(const float4*)(wr);
        float4 w1 = *(const float4*)(wr + 4);
        f16x8 h8;
        h8[0]=(_Float16)(w0.x*scale); h8[1]=(_Float16)(w0.y*scale);
        h8[2]=(_Float16)(w0.z*scale); h8[3]=(_Float16)(w0.w*scale);
        h8[4]=(_Float16)(w1.x*scale); h8[5]=(_Float16)(w1.y*scale);
        h8[6]=(_Float16)(w1.z*scale); h8[7]=(_Float16)(w1.w*scale);
        WH[a] = h8;
        f16x8 x8;
        if (quad < 2) {
            const float* xr = W_ih + n * 16 + quad * 8;
            float4 u0 = *(const float4*)(xr);
            float4 u1 = *(const float4*)(xr + 4);
            x8[0]=(_Float16)(u0.x*scale); x8[1]=(_Float16)(u0.y*scale);
            x8[2]=(_Float16)(u0.z*scale); x8[3]=(_Float16)(u0.w*scale);
            x8[4]=(_Float16)(u1.x*scale); x8[5]=(_Float16)(u1.y*scale);
            x8[6]=(_Float16)(u1.z*scale); x8[7]=(_Float16)(u1.w*scale);
        } else {
            #pragma unroll
            for (int jj = 0; jj < 8; ++jj) x8[jj] = (_Float16)0.0f;
        }
        WX[a] = x8;
        const int nb = gate * 32 + 8 * quad + 4 * (a & 1);
        float4 bi = *(const float4*)(b_ih + nb);
        float4 bh = *(const float4*)(b_hh + nb);
        f32x4 bb = {(bi.x+bh.x)*scale, (bi.y+bh.y)*scale,
                    (bi.z+bh.z)*scale, (bi.w+bh.w)*scale};
        bias[a] = bb;
    }

    __syncthreads();   // staging visible

    // ---- recurrence: barrier-free, ROLLED loop (code fits I$) ----
    const bool qlow = (quad < 2);
    int xaddr = qlow ? (cidx * XSTRIDE + quad * 16) : ZOFF;
    const int xinc = qlow ? 32 : 0;

    f16x8 xfrag = *(const f16x8*)(smem + xaddr); xaddr += xinc;
    f32x4 accp[8];
    #pragma unroll
    for (int a = 0; a < 8; ++a)
        accp[a] = __builtin_amdgcn_mfma_f32_16x16x32_f16(WX[a], xfrag, bias[a], 0, 0, 0);

    union { int i[4]; f16x8 v; } hf;
    hf.i[0]=0; hf.i[1]=0; hf.i[2]=0; hf.i[3]=0;
    const f32x2 zz = {0.0f, 0.0f};
    f32x2 cst[4] = {zz, zz, zz, zz};
    f32x2 hv[4];
    const f32x2 one = {1.0f, 1.0f};

    #pragma unroll 1
    for (int t = 0; t < 32; ++t) {
        f32x4 acc[8];
        #pragma unroll
        for (int a = 0; a < 8; ++a)
            acc[a] = __builtin_amdgcn_mfma_f32_16x16x32_f16(WH[a], hf.v, accp[a], 0, 0, 0);

        f16x8 xn = *(const f16x8*)(smem + xaddr); xaddr += xinc;

        // 4 independent activation chains (v15 algebra: all trans-unit)
        #pragma unroll
        for (int cc = 0; cc < 4; ++cc) {
            const int sel = cc >> 1;
            const int r0  = (cc & 1) << 1;
            f32x2 zi = {acc[0+sel][r0], acc[0+sel][r0+1]};
            f32x2 zf = {acc[2+sel][r0], acc[2+sel][r0+1]};
            f32x2 zg = {acc[4+sel][r0], acc[4+sel][r0+1]};
            f32x2 zo = {acc[6+sel][r0], acc[6+sel][r0+1]};
            f32x2 Ei = {__builtin_amdgcn_exp2f(zi.x), __builtin_amdgcn_exp2f(zi.y)};
            f32x2 Ef = {__builtin_amdgcn_exp2f(zf.x), __builtin_amdgcn_exp2f(zf.y)};
            f32x2 Eg = {__builtin_amdgcn_exp2f(zg.x), __builtin_amdgcn_exp2f(zg.y)};
            f32x2 Eo = {__builtin_amdgcn_exp2f(zo.x), __builtin_amdgcn_exp2f(zo.y)};
            f32x2 t1  = Ei + one;
            f32x2 dig = t1 * Eg + t1;                 // (1+Ei)(1+Eg)
            f32x2 tf  = Ef + one;
            f32x2 nn  = (Eg - one) * tf + cst[cc] * dig;
            f32x2 den = tf * dig;
            f32x2 rde = {__builtin_amdgcn_rcpf(den.x), __builtin_amdgcn_rcpf(den.y)};
            f32x2 c   = nn * rde;
            cst[cc] = c;
            f32x2 cl  = c * TWO_LOG2E;
            f32x2 Ec  = {__builtin_amdgcn_exp2f(cl.x), __builtin_amdgcn_exp2f(cl.y)};
            f32x2 to  = Eo + one;
            f32x2 dh  = to * Ec + to;                 // (1+Eo)(1+Ec)
            f32x2 rdh = {__builtin_amdgcn_rcpf(dh.x), __builtin_amdgcn_rcpf(dh.y)};
            hv[cc] = (Ec - one) * rdh;
            union { fp16x2 h; int i; } pk;
            pk.h = __builtin_amdgcn_cvt_pkrtz(hv[cc].x, hv[cc].y);
            hf.i[cc] = pk.i;   // dword cc = B-frag k = 8*quad + {2cc, 2cc+1}
        }

        #pragma unroll
        for (int a = 0; a < 8; ++a)
            accp[a] = __builtin_amdgcn_mfma_f32_16x16x32_f16(WX[a], xn, bias[a], 0, 0, 0);
    }

    // ---- fc2 epilogue (wave-local) ----
    __syncthreads();
    {
        char* s0 = smem + cidx * 144 + quad * 32;
        float4 lo4 = {hv[0].x, hv[0].y, hv[1].x, hv[1].y};
        float4 hi4 = {hv[2].x, hv[2].y, hv[3].x, hv[3].y};
        *(float4*)s0        = lo4;
        *(float4*)(s0 + 16) = hi4;
    }
    __syncthreads();
    {
        const int b = lane >> 2, j = lane & 3;
        const float* hrow = (const float*)(smem + b * 144);
        const float* fw = fc2_W + j * 32;
        float s = fc2_b[j];
        #pragma unroll
        for (int k = 0; k < 8; ++k) {
            float4 hvv = *(const float4*)(hrow + k * 4);
            float4 wv4 = *(const float4*)(fw + k * 4);
            s += wv4.x*hvv.x + wv4.y*hvv.y + wv4.z*hvv.z + wv4.w*hvv.w;
        }
        s = fminf(fmaxf(s, 0.0f), 1.0f);
        out[(long)blockIdx.x * 64 + lane] = s;
    }
}

extern "C" void kernel_launch(void* const* d_in, const int* in_sizes, int n_in,
                              void* d_out, int out_size, void* d_ws, size_t ws_size,
                              hipStream_t stream)
{
    // inputs: 0 objs(i32) 1 boxes(f32) 2 preds(i32) 3 subj(i32) 4 target(unused)
    //         5 obj_emb 6 pred_emb 7 W_ih 8 W_hh 9 b_ih 10 b_hh 11 fc2_W 12 fc2_b
    lstm_fused<<<2048, 64, LDS_BYTES, stream>>>(
        (const int*)d_in[0], (const float*)d_in[1], (const int*)d_in[2],
        (const int*)d_in[3],
        (const float*)d_in[5], (const float*)d_in[6],
        (const float*)d_in[7], (const float*)d_in[8],
        (const float*)d_in[9], (const float*)d_in[10],
        (const float*)d_in[11], (const float*)d_in[12],
        (float*)d_out);
}